// Round 18
// baseline (268.449 us; speedup 1.0000x reference)
//
#include <hip/hip_runtime.h>
#include <hip/hip_bf16.h>

#define BB   8
#define SS   512
#define DD   128
#define HH   512
#define NBK  32

// ---- XCD-aware grids: gridDim.x = 8 = batch, so linear%8 == batch ----------

// ------- K2: q,v = x@W+b + LSH bucket ids + qT; enc0 fuses embedding ---------
__global__ __launch_bounds__(512) void k_qvb(const float* __restrict__ x,
        const int* __restrict__ idx, const float* __restrict__ emb,
        const float* __restrict__ pe, int use_emb,
        const float* __restrict__ Wq, const float* __restrict__ bq,
        const float* __restrict__ Wv, const float* __restrict__ bv,
        const float* __restrict__ hyp,
        float* __restrict__ q, float* __restrict__ v, float* __restrict__ qT,
        int* __restrict__ bucket) {
    int rb = blockIdx.x * 32 + blockIdx.y;         // batch-major: XCD = batch
    __shared__ __align__(16) float xs[16][132];
    __shared__ float qts[128][17];                 // transposed q strip
    int tid = threadIdx.x;
    {
        int r = tid >> 5, kq = (tid & 31) * 4;     // 512 float4 slots, 1/thread
        int tokg = rb * 16 + r;
        float4 xv;
        if (use_emb) {
            int e = idx[tokg];
            xv = *(const float4*)&emb[(size_t)e * DD + kq];
            float4 pv = *(const float4*)&pe[blockIdx.x * DD + kq];
            xv.x += pv.x; xv.y += pv.y; xv.z += pv.z; xv.w += pv.w;
        } else {
            xv = *(const float4*)&x[(size_t)tokg * DD + kq];
        }
        *(float4*)&xs[r][kq] = xv;
    }
    __syncthreads();
    int half = tid >> 8;                           // 0 = q, 1 = v
    int tx = tid & 63;                             // col pair
    int ty = (tid >> 6) & 3;                       // row quad (= wave id in half)
    const float* W    = half ? Wv : Wq;
    const float* bias = half ? bv : bq;
    float* outp       = half ? v  : q;
    float2 acc[4];
    #pragma unroll
    for (int i = 0; i < 4; ++i) acc[i] = make_float2(0.f, 0.f);
    for (int g = 0; g < 32; ++g) {
        int kb = g * 4;
        float4 a0 = *(const float4*)&xs[ty * 4 + 0][kb];
        float4 a1 = *(const float4*)&xs[ty * 4 + 1][kb];
        float4 a2 = *(const float4*)&xs[ty * 4 + 2][kb];
        float4 a3 = *(const float4*)&xs[ty * 4 + 3][kb];
        #pragma unroll
        for (int j = 0; j < 4; ++j) {
            float2 w = *(const float2*)&W[(size_t)(kb + j) * DD + tx * 2];
            float c0 = (j == 0) ? a0.x : (j == 1) ? a0.y : (j == 2) ? a0.z : a0.w;
            float c1 = (j == 0) ? a1.x : (j == 1) ? a1.y : (j == 2) ? a1.z : a1.w;
            float c2 = (j == 0) ? a2.x : (j == 1) ? a2.y : (j == 2) ? a2.z : a2.w;
            float c3 = (j == 0) ? a3.x : (j == 1) ? a3.y : (j == 2) ? a3.z : a3.w;
            acc[0].x += c0 * w.x; acc[0].y += c0 * w.y;
            acc[1].x += c1 * w.x; acc[1].y += c1 * w.y;
            acc[2].x += c2 * w.x; acc[2].y += c2 * w.y;
            acc[3].x += c3 * w.x; acc[3].y += c3 * w.y;
        }
    }
    float2 bi = *(const float2*)&bias[tx * 2];
    float2 o[4];
    #pragma unroll
    for (int i = 0; i < 4; ++i) {
        o[i] = make_float2(acc[i].x + bi.x, acc[i].y + bi.y);
        int row = rb * 16 + ty * 4 + i;
        *(float2*)&outp[(size_t)row * DD + tx * 2] = o[i];
    }
    if (half == 0) {
        #pragma unroll
        for (int i = 0; i < 4; ++i) {
            qts[2 * tx][ty * 4 + i]     = o[i].x;
            qts[2 * tx + 1][ty * 4 + i] = o[i].y;
        }
        float h0[5], h1[5];
        #pragma unroll
        for (int h = 0; h < 5; ++h) {
            h0[h] = hyp[(2 * tx) * 5 + h];
            h1[h] = hyp[(2 * tx + 1) * 5 + h];
        }
        float pr[4][5];
        #pragma unroll
        for (int r = 0; r < 4; ++r)
            #pragma unroll
            for (int h = 0; h < 5; ++h)
                pr[r][h] = o[r].x * h0[h] + o[r].y * h1[h];
        #pragma unroll
        for (int off = 1; off < 64; off <<= 1)
            #pragma unroll
            for (int r = 0; r < 4; ++r)
                #pragma unroll
                for (int h = 0; h < 5; ++h)
                    pr[r][h] += __shfl_xor(pr[r][h], off, 64);
        if (tx == 0) {
            #pragma unroll
            for (int r = 0; r < 4; ++r) {
                int bb = 0;
                #pragma unroll
                for (int h = 0; h < 5; ++h)
                    if (pr[r][h] + hyp[128 * 5 + h] >= 0.f) bb |= (1 << h);
                bucket[rb * 16 + ty * 4 + r] = bb;
            }
        }
    }
    __syncthreads();
    {
        int b  = blockIdx.x;
        int t0 = blockIdx.y * 16;
        int k  = tid >> 2, oo = (tid & 3) * 4;
        float4 v0 = make_float4(qts[k][oo], qts[k][oo + 1], qts[k][oo + 2], qts[k][oo + 3]);
        *(float4*)&qT[((size_t)b * DD + k) * SS + t0 + oo] = v0;
    }
}

// ------- K3: Vb[b][bk][:] + cnt; 512 threads, 4-way token split --------------
__global__ __launch_bounds__(512) void k_vb(const float* __restrict__ v,
        const int* __restrict__ bucket, float* __restrict__ Vb,
        int* __restrict__ cnt) {
    int b  = blockIdx.x;                           // 0..7  (XCD = batch)
    int bk = blockIdx.y;                           // 0..31
    int tid = threadIdx.x;
    __shared__ int bkt_sh[512];
    __shared__ float red[3][128];
    bkt_sh[tid] = bucket[b * SS + tid];
    __syncthreads();
    int d = tid & 127, part = tid >> 7;            // 4 parts x 128 tokens
    const float* vbp = v + (size_t)b * SS * DD + d;
    float acc = 0.f;
    #pragma unroll 8
    for (int i = 0; i < 128; ++i) {
        int tok = part * 128 + i;
        float val = vbp[(size_t)tok * DD];
        acc += (bkt_sh[tok] == bk) ? val : 0.f;
    }
    if (part > 0) red[part - 1][d] = acc;
    __syncthreads();
    if (part == 0)
        Vb[(size_t)((b << 5) + bk) * DD + d] = acc + red[0][d] + red[1][d] + red[2][d];
    if (tid < 64) {
        int c = 0;
        #pragma unroll
        for (int i = 0; i < 8; ++i) c += (bkt_sh[tid * 8 + i] == bk) ? 1 : 0;
        #pragma unroll
        for (int o = 1; o < 64; o <<= 1) c += __shfl_xor(c, o, 64);
        if (tid == 0) cnt[(b << 5) + bk] = c;
    }
}

// ------ K5: fused encoder layer; 1024 threads = 16 waves/CU ------------------
__global__ __launch_bounds__(1024, 4) void k_enc(const float* __restrict__ qT,
        const float* __restrict__ q, const float* __restrict__ v,
        const int* __restrict__ bucket, const int* __restrict__ cnt,
        const float* __restrict__ Vb,
        const float* __restrict__ g, const float* __restrict__ lb,
        const float* __restrict__ W1, const float* __restrict__ b1,
        const float* __restrict__ W2, const float* __restrict__ b2,
        float* __restrict__ x) {
    int bz = blockIdx.x, s0 = blockIdx.y * 16;     // XCD = batch
    int tid = threadIdx.x;
    __shared__ __align__(16) float qs[16][128];    // q strip -> LN(attn) -> ffn in/residual
    __shared__ __align__(16) float cs[16][512];    // G -> e -> c -> (reuse) h
    __shared__ __align__(16) float osh[8][16][128];// split-K8 partials (64 KB)
    __shared__ int   bkt[512];
    __shared__ float Wsh[16][32];
    __shared__ float rsh[16][32];
    __shared__ float Msh[16];
    __shared__ float cntf[32];
    __shared__ int   bssh[16];
    {
        int r = tid >> 6, kq = (tid & 63) * 2;
        *(float2*)&qs[r][kq] = *(const float2*)&q[(size_t)(bz * SS + s0 + r) * DD + kq];
    }
    if (tid < 512) bkt[tid] = bucket[bz * SS + tid];
    if (tid < 32) cntf[tid] = (float)cnt[(bz << 5) + tid];
    if (tid < 16) bssh[tid] = bucket[bz * SS + s0 + tid];
    if (tid < 512) Wsh[tid >> 5][tid & 31] = 0.f;
    __syncthreads();
    const float scale = 0.088388347648318447f;
    // ---- Phase G: split-K2 x 2 row-octets x 256 col-pairs, 8-row micro ----
    {
        int kh   = tid >> 9;                       // 0..1 : k half (64)
        int rg   = (tid >> 8) & 1;                 // row octet 0..1
        int slot = tid & 255;                      // col pair (512 cols)
        float2 acc[8];
        #pragma unroll
        for (int i = 0; i < 8; ++i) acc[i] = make_float2(0.f, 0.f);
        const float* qtb = qT + (size_t)bz * DD * SS + (size_t)kh * 64 * SS + slot * 2;
        for (int gg = 0; gg < 16; ++gg) {
            int kb = kh * 64 + gg * 4;
            float4 a[8];
            #pragma unroll
            for (int i = 0; i < 8; ++i) a[i] = *(const float4*)&qs[rg * 8 + i][kb];
            #pragma unroll
            for (int j = 0; j < 4; ++j) {
                float2 b2v = *(const float2*)&qtb[(size_t)(gg * 4 + j) * SS];
                #pragma unroll
                for (int i = 0; i < 8; ++i) {
                    float c = (j == 0) ? a[i].x : (j == 1) ? a[i].y : (j == 2) ? a[i].z : a[i].w;
                    acc[i].x += c * b2v.x; acc[i].y += c * b2v.y;
                }
            }
        }
        if (kh == 1) {
            #pragma unroll
            for (int i = 0; i < 8; ++i)
                *(float2*)&cs[rg * 8 + i][slot * 2] = acc[i];
        }
        __syncthreads();
        if (kh == 0) {
            #pragma unroll
            for (int i = 0; i < 8; ++i) {
                float2 p = *(const float2*)&cs[rg * 8 + i][slot * 2];
                p.x = (p.x + acc[i].x) * scale;
                p.y = (p.y + acc[i].y) * scale;
                *(float2*)&cs[rg * 8 + i][slot * 2] = p;
            }
        }
        __syncthreads();
    }
    // ---- fused row-max + exp + per-bucket sums : 16 rows x 64 lanes ----
    int row = tid >> 6, l = tid & 63;
    {
        float vals[8];
        float m = 0.f;
        #pragma unroll
        for (int i = 0; i < 8; ++i) {
            vals[i] = cs[row][l + 64 * i];
            m = fmaxf(m, vals[i]);
        }
        #pragma unroll
        for (int o = 1; o < 64; o <<= 1) m = fmaxf(m, __shfl_xor(m, o, 64));
        if (l == 0) Msh[row] = m;
        #pragma unroll
        for (int i = 0; i < 8; ++i) {
            int c = l + 64 * i;
            float ev = __expf(vals[i] - m);
            cs[row][c] = ev;
            atomicAdd(&Wsh[row][bkt[c]], ev);
        }
    }
    __syncthreads();
    // ---- rsh with Z folded in (broadcast LDS reads, free) ----
    if (tid < 512) {
        int r = tid >> 5, bkid = tid & 31;
        float z = 0.f;
        #pragma unroll
        for (int i = 0; i < NBK; ++i) z += Wsh[r][i];
        rsh[r][bkid] = 1.0f / (z - Wsh[r][bkid] + cntf[bkid] * __expf(-Msh[r]));
    }
    __syncthreads();
    // ---- transform c = e * (R - r_{b_t}) with R folded in ----
    {
        int bs = bssh[row];
        float R = 0.f;
        #pragma unroll
        for (int i = 0; i < NBK; ++i) R += (i == bs) ? 0.f : rsh[row][i];
        #pragma unroll
        for (int i = 0; i < 8; ++i) {
            int c = l + 64 * i;
            int bc = bkt[c];
            float rsel = (bc == bs) ? 0.f : rsh[row][bc];
            cs[row][c] *= (R - rsel);
        }
    }
    __syncthreads();
    // ---- C@V: split-K8 x 4 row-quads x 32 col-quads; partials -> osh[kh] ----
    {
        int kh = tid >> 7;                         // 0..7 : k chunk of 64
        int rg = (tid >> 5) & 3;                   // row quad
        int cp = tid & 31;                         // col quad over D
        float4 acc[4];
        #pragma unroll
        for (int i = 0; i < 4; ++i) acc[i] = make_float4(0.f, 0.f, 0.f, 0.f);
        const float* vb_base = v + (size_t)bz * SS * DD + cp * 4;
        for (int gg = 0; gg < 16; ++gg) {
            int kb = kh * 64 + gg * 4;
            float4 a[4];
            #pragma unroll
            for (int i = 0; i < 4; ++i) a[i] = *(const float4*)&cs[rg * 4 + i][kb];
            #pragma unroll
            for (int j = 0; j < 4; ++j) {
                float4 vj = *(const float4*)&vb_base[(size_t)(kb + j) * DD];
                #pragma unroll
                for (int i = 0; i < 4; ++i) {
                    float c = (j == 0) ? a[i].x : (j == 1) ? a[i].y : (j == 2) ? a[i].z : a[i].w;
                    acc[i].x += c * vj.x; acc[i].y += c * vj.y;
                    acc[i].z += c * vj.z; acc[i].w += c * vj.w;
                }
            }
        }
        if (kh == 0) {                             // fold uniform term into kh0 partial
            float4 vs = make_float4(0.f, 0.f, 0.f, 0.f);
            #pragma unroll
            for (int i = 0; i < NBK; ++i) {
                float4 t = *(const float4*)&Vb[(size_t)((bz << 5) + i) * DD + cp * 4];
                vs.x += t.x; vs.y += t.y; vs.z += t.z; vs.w += t.w;
            }
            const float inv512 = 1.0f / 512.0f;
            #pragma unroll
            for (int i = 0; i < 4; ++i) {
                int r = rg * 4 + i;
                int bs = bssh[r];
                float4 vb4 = *(const float4*)&Vb[(size_t)((bz << 5) + bs) * DD + cp * 4];
                acc[i].x += (vs.x - vb4.x) * inv512;
                acc[i].y += (vs.y - vb4.y) * inv512;
                acc[i].z += (vs.z - vb4.z) * inv512;
                acc[i].w += (vs.w - vb4.w) * inv512;
            }
        }
        #pragma unroll
        for (int i = 0; i < 4; ++i)
            *(float4*)&osh[kh][rg * 4 + i][cp * 4] = acc[i];
        __syncthreads();
    }
    // ---- LayerNorm(attn), merging 8 partials -> qs (ffn input + residual) ----
    {
        float2 val = make_float2(0.f, 0.f);
        #pragma unroll
        for (int p = 0; p < 8; ++p) {
            float2 t = *(const float2*)&osh[p][row][l * 2];
            val.x += t.x; val.y += t.y;
        }
        float s = val.x + val.y;
        float ss = val.x * val.x + val.y * val.y;
        #pragma unroll
        for (int o = 1; o < 64; o <<= 1) {
            s  += __shfl_xor(s, o, 64);
            ss += __shfl_xor(ss, o, 64);
        }
        float mean = s * (1.f / 128.f);
        float var = ss * (1.f / 128.f) - mean * mean;
        float rstd = rsqrtf(var + 1e-5f);
        float2 gv = *(const float2*)&g[l * 2];
        float2 bv = *(const float2*)&lb[l * 2];
        float2 out;
        out.x = (val.x - mean) * rstd * gv.x + bv.x;
        out.y = (val.y - mean) * rstd * gv.y + bv.y;
        *(float2*)&qs[row][l * 2] = out;
    }
    __syncthreads();
    // ---- Phase B: h = relu(qs@W1+b1) -> cs; split-K2 x 256 col-pairs ----
    {
        int kh   = tid >> 9;                       // 0..1 : k half (64)
        int rg   = (tid >> 8) & 1;                 // row octet
        int slot = tid & 255;                      // col pair (512 cols)
        float2 acc[8];
        #pragma unroll
        for (int i = 0; i < 8; ++i) acc[i] = make_float2(0.f, 0.f);
        for (int gg = 0; gg < 16; ++gg) {
            int kb = kh * 64 + gg * 4;
            float4 a[8];
            #pragma unroll
            for (int i = 0; i < 8; ++i) a[i] = *(const float4*)&qs[rg * 8 + i][kb];
            #pragma unroll
            for (int j = 0; j < 4; ++j) {
                float2 w2v = *(const float2*)&W1[(size_t)(kb + j) * HH + slot * 2];
                #pragma unroll
                for (int i = 0; i < 8; ++i) {
                    float c = (j == 0) ? a[i].x : (j == 1) ? a[i].y : (j == 2) ? a[i].z : a[i].w;
                    acc[i].x += c * w2v.x; acc[i].y += c * w2v.y;
                }
            }
        }
        if (kh == 1) {
            #pragma unroll
            for (int i = 0; i < 8; ++i)
                *(float2*)&cs[rg * 8 + i][slot * 2] = acc[i];
        }
        __syncthreads();
        if (kh == 0) {
            float2 bi = *(const float2*)&b1[slot * 2];
            #pragma unroll
            for (int i = 0; i < 8; ++i) {
                float2 p = *(const float2*)&cs[rg * 8 + i][slot * 2];
                p.x = fmaxf(p.x + acc[i].x + bi.x, 0.f);
                p.y = fmaxf(p.y + acc[i].y + bi.y, 0.f);
                *(float2*)&cs[rg * 8 + i][slot * 2] = p;
            }
        }
        __syncthreads();
    }
    // ---- Phase C: y = h@W2 (+b2+residual in kh0); split-K8 -> osh[kh] ----
    {
        int kh = tid >> 7;                         // 0..7 : k chunk of 64
        int rg = (tid >> 5) & 3;                   // row quad
        int cp = tid & 31;                         // col quad over D
        float4 acc[4];
        #pragma unroll
        for (int i = 0; i < 4; ++i) acc[i] = make_float4(0.f, 0.f, 0.f, 0.f);
        for (int gg = 0; gg < 16; ++gg) {
            int kb = kh * 64 + gg * 4;
            float4 a[4];
            #pragma unroll
            for (int i = 0; i < 4; ++i) a[i] = *(const float4*)&cs[rg * 4 + i][kb];
            #pragma unroll
            for (int j = 0; j < 4; ++j) {
                float4 w = *(const float4*)&W2[(size_t)(kb + j) * DD + cp * 4];
                #pragma unroll
                for (int i = 0; i < 4; ++i) {
                    float c = (j == 0) ? a[i].x : (j == 1) ? a[i].y : (j == 2) ? a[i].z : a[i].w;
                    acc[i].x += c * w.x; acc[i].y += c * w.y;
                    acc[i].z += c * w.z; acc[i].w += c * w.w;
                }
            }
        }
        if (kh == 0) {
            float4 bi = *(const float4*)&b2[cp * 4];
            #pragma unroll
            for (int i = 0; i < 4; ++i) {
                int r = rg * 4 + i;
                float4 res = *(const float4*)&qs[r][cp * 4];
                acc[i].x += bi.x + res.x;
                acc[i].y += bi.y + res.y;
                acc[i].z += bi.z + res.z;
                acc[i].w += bi.w + res.w;
            }
        }
        #pragma unroll
        for (int i = 0; i < 4; ++i)
            *(float4*)&osh[kh][rg * 4 + i][cp * 4] = acc[i];
        __syncthreads();
    }
    // ---- LayerNorm(ffn), merging 8 partials -> global x ----
    {
        float2 val = make_float2(0.f, 0.f);
        #pragma unroll
        for (int p = 0; p < 8; ++p) {
            float2 t = *(const float2*)&osh[p][row][l * 2];
            val.x += t.x; val.y += t.y;
        }
        float s = val.x + val.y;
        float ss = val.x * val.x + val.y * val.y;
        #pragma unroll
        for (int o = 1; o < 64; o <<= 1) {
            s  += __shfl_xor(s, o, 64);
            ss += __shfl_xor(ss, o, 64);
        }
        float mean = s * (1.f / 128.f);
        float var = ss * (1.f / 128.f) - mean * mean;
        float rstd = rsqrtf(var + 1e-5f);
        float2 gv = *(const float2*)&g[l * 2];
        float2 bv = *(const float2*)&lb[l * 2];
        float2 out;
        out.x = (val.x - mean) * rstd * gv.x + bv.x;
        out.y = (val.y - mean) * rstd * gv.y + bv.y;
        *(float2*)&x[(size_t)(bz * SS + s0 + row) * DD + l * 2] = out;
    }
}

// ---------------- K9: out = x_flat @ Wm + bm (split-K + atomics) -------------
__global__ __launch_bounds__(256) void k_final(const float* __restrict__ x,
        const float* __restrict__ Wm, const float* __restrict__ bm,
        float* __restrict__ out) {
    int b = blockIdx.x, chunk = blockIdx.y;        // XCD = batch; 2048 elems/chunk
    int tid = threadIdx.x;
    const float* xr = x + (size_t)b * 65536 + chunk * 2048;
    const float* wr = Wm + (size_t)(chunk * 2048) * 6;
    float p[6] = {0.f, 0.f, 0.f, 0.f, 0.f, 0.f};
    #pragma unroll
    for (int it = 0; it < 2; ++it) {
        int j = (tid + 256 * it) * 4;              // float4 over 2048 elems
        float4 xv = *(const float4*)&xr[j];
        const float* w = wr + (size_t)j * 6;
        float4 w0 = *(const float4*)&w[0];
        float4 w1 = *(const float4*)&w[4];
        float4 w2 = *(const float4*)&w[8];
        float4 w3 = *(const float4*)&w[12];
        float4 w4 = *(const float4*)&w[16];
        float4 w5 = *(const float4*)&w[20];
        p[0] += xv.x * w0.x + xv.y * w1.z + xv.z * w3.x + xv.w * w4.z;
        p[1] += xv.x * w0.y + xv.y * w1.w + xv.z * w3.y + xv.w * w4.w;
        p[2] += xv.x * w0.z + xv.y * w2.x + xv.z * w3.z + xv.w * w5.x;
        p[3] += xv.x * w0.w + xv.y * w2.y + xv.z * w3.w + xv.w * w5.y;
        p[4] += xv.x * w1.x + xv.y * w2.z + xv.z * w4.x + xv.w * w5.z;
        p[5] += xv.x * w1.y + xv.y * w2.w + xv.z * w4.y + xv.w * w5.w;
    }
    #pragma unroll
    for (int o = 0; o < 6; ++o)
        #pragma unroll
        for (int off = 1; off < 64; off <<= 1)
            p[o] += __shfl_xor(p[o], off, 64);
    __shared__ float red[4][6];
    int wv = tid >> 6;
    if ((tid & 63) == 0)
        #pragma unroll
        for (int o = 0; o < 6; ++o) red[wv][o] = p[o];
    __syncthreads();
    if (tid < 6) {
        float sv = red[0][tid] + red[1][tid] + red[2][tid] + red[3][tid];
        if (chunk == 0) sv += bm[tid];
        atomicAdd(&out[b * 6 + tid], sv);
    }
}

// ---------------- orchestration ----------------------------------------------
extern "C" void kernel_launch(void* const* d_in, const int* in_sizes, int n_in,
                              void* d_out, int out_size, void* d_ws, size_t ws_size,
                              hipStream_t stream) {
    const int*   inputs = (const int*)  d_in[0];
    const float* emb    = (const float*)d_in[1];
    const float* pe     = (const float*)d_in[2];
    const float* hyp    = (const float*)d_in[3];
    const float* Wq     = (const float*)d_in[4];
    const float* bq     = (const float*)d_in[5];
    const float* Wv     = (const float*)d_in[6];
    const float* bv     = (const float*)d_in[7];
    const float* ln_g   = (const float*)d_in[8];
    const float* ln_b   = (const float*)d_in[9];
    const float* W1     = (const float*)d_in[10];
    const float* b1     = (const float*)d_in[11];
    const float* W2     = (const float*)d_in[12];
    const float* b2     = (const float*)d_in[13];
    const float* Wm     = (const float*)d_in[14];
    const float* bm     = (const float*)d_in[15];

    float* F = (float*)d_ws;
    float* x     = F + 0;          // 524288
    float* q     = F + 524288;     // 524288
    float* v     = F + 1048576;    // 524288
    float* qT    = F + 1572864;    // 524288  [b][k][t]
    float* Vb    = F + 2097152;    // 32768   (plain stores)
    int*   cnt   = (int*)(F + 2129920);  // 256 ints
    int*   bucket= (int*)(F + 2130176);  // 4096 ints

    hipMemsetAsync(d_out, 0, (size_t)out_size * 4, stream);

    for (int enc = 0; enc < 2; ++enc) {
        k_qvb<<<dim3(8, 32), 512, 0, stream>>>(x, inputs, emb, pe, enc == 0 ? 1 : 0,
                                               Wq, bq, Wv, bv, hyp, q, v, qT, bucket);
        k_vb<<<dim3(8, 32), 512, 0, stream>>>(v, bucket, Vb, cnt);
        k_enc<<<dim3(8, 32), 1024, 0, stream>>>(qT, q, v, bucket, cnt, Vb,
                                                ln_g, ln_b, W1, b1, W2, b2, x);
    }
    k_final<<<dim3(8, 32), 256, 0, stream>>>(x, Wm, bm, (float*)d_out);
}

// Round 19
// 232.572 us; speedup vs baseline: 1.1543x; 1.1543x over previous
//
#include <hip/hip_runtime.h>
#include <hip/hip_bf16.h>

#define BB   8
#define SS   512
#define DD   128
#define HH   512
#define NBK  32

// ---- XCD-aware grids: gridDim.x = 8 = batch, so linear%8 == batch ----------

// ------- K2: q,v = x@W+b + LSH bucket ids + qT; enc0 fuses embedding ---------
// 512 threads: tid<256 computes q (+LSH), tid>=256 computes v. 8 waves/CU.
__global__ __launch_bounds__(512) void k_qvb(const float* __restrict__ x,
        const int* __restrict__ idx, const float* __restrict__ emb,
        const float* __restrict__ pe, int use_emb,
        const float* __restrict__ Wq, const float* __restrict__ bq,
        const float* __restrict__ Wv, const float* __restrict__ bv,
        const float* __restrict__ hyp,
        float* __restrict__ q, float* __restrict__ v, float* __restrict__ qT,
        int* __restrict__ bucket) {
    int rb = blockIdx.x * 32 + blockIdx.y;         // batch-major: XCD = batch
    __shared__ __align__(16) float xs[16][132];
    __shared__ float qts[128][17];                 // transposed q strip
    int tid = threadIdx.x;
    {
        int r = tid >> 5, kq = (tid & 31) * 4;     // 512 float4 slots, 1/thread
        int tokg = rb * 16 + r;
        float4 xv;
        if (use_emb) {
            int e = idx[tokg];
            xv = *(const float4*)&emb[(size_t)e * DD + kq];
            float4 pv = *(const float4*)&pe[blockIdx.x * DD + kq];
            xv.x += pv.x; xv.y += pv.y; xv.z += pv.z; xv.w += pv.w;
        } else {
            xv = *(const float4*)&x[(size_t)tokg * DD + kq];
        }
        *(float4*)&xs[r][kq] = xv;
    }
    __syncthreads();
    int half = tid >> 8;                           // 0 = q, 1 = v
    int tx = tid & 63;                             // col pair
    int ty = (tid >> 6) & 3;                       // row quad (= wave id in half)
    const float* W    = half ? Wv : Wq;
    const float* bias = half ? bv : bq;
    float* outp       = half ? v  : q;
    float2 acc[4];
    #pragma unroll
    for (int i = 0; i < 4; ++i) acc[i] = make_float2(0.f, 0.f);
    for (int g = 0; g < 32; ++g) {
        int kb = g * 4;
        float4 a0 = *(const float4*)&xs[ty * 4 + 0][kb];
        float4 a1 = *(const float4*)&xs[ty * 4 + 1][kb];
        float4 a2 = *(const float4*)&xs[ty * 4 + 2][kb];
        float4 a3 = *(const float4*)&xs[ty * 4 + 3][kb];
        #pragma unroll
        for (int j = 0; j < 4; ++j) {
            float2 w = *(const float2*)&W[(size_t)(kb + j) * DD + tx * 2];
            float c0 = (j == 0) ? a0.x : (j == 1) ? a0.y : (j == 2) ? a0.z : a0.w;
            float c1 = (j == 0) ? a1.x : (j == 1) ? a1.y : (j == 2) ? a1.z : a1.w;
            float c2 = (j == 0) ? a2.x : (j == 1) ? a2.y : (j == 2) ? a2.z : a2.w;
            float c3 = (j == 0) ? a3.x : (j == 1) ? a3.y : (j == 2) ? a3.z : a3.w;
            acc[0].x += c0 * w.x; acc[0].y += c0 * w.y;
            acc[1].x += c1 * w.x; acc[1].y += c1 * w.y;
            acc[2].x += c2 * w.x; acc[2].y += c2 * w.y;
            acc[3].x += c3 * w.x; acc[3].y += c3 * w.y;
        }
    }
    float2 bi = *(const float2*)&bias[tx * 2];
    float2 o[4];
    #pragma unroll
    for (int i = 0; i < 4; ++i) {
        o[i] = make_float2(acc[i].x + bi.x, acc[i].y + bi.y);
        int row = rb * 16 + ty * 4 + i;
        *(float2*)&outp[(size_t)row * DD + tx * 2] = o[i];
    }
    if (half == 0) {
        // LDS transpose of q for qT
        #pragma unroll
        for (int i = 0; i < 4; ++i) {
            qts[2 * tx][ty * 4 + i]     = o[i].x;
            qts[2 * tx + 1][ty * 4 + i] = o[i].y;
        }
        // LSH projection: 5 hyperplanes; butterfly over the 64-lane wave
        float h0[5], h1[5];
        #pragma unroll
        for (int h = 0; h < 5; ++h) {
            h0[h] = hyp[(2 * tx) * 5 + h];
            h1[h] = hyp[(2 * tx + 1) * 5 + h];
        }
        float pr[4][5];
        #pragma unroll
        for (int r = 0; r < 4; ++r)
            #pragma unroll
            for (int h = 0; h < 5; ++h)
                pr[r][h] = o[r].x * h0[h] + o[r].y * h1[h];
        #pragma unroll
        for (int off = 1; off < 64; off <<= 1)
            #pragma unroll
            for (int r = 0; r < 4; ++r)
                #pragma unroll
                for (int h = 0; h < 5; ++h)
                    pr[r][h] += __shfl_xor(pr[r][h], off, 64);
        if (tx == 0) {
            #pragma unroll
            for (int r = 0; r < 4; ++r) {
                int bb = 0;
                #pragma unroll
                for (int h = 0; h < 5; ++h)
                    if (pr[r][h] + hyp[128 * 5 + h] >= 0.f) bb |= (1 << h);
                bucket[rb * 16 + ty * 4 + r] = bb;
            }
        }
    }
    __syncthreads();
    // write qT[b][k][t]: 512 threads, one float4 each
    {
        int b  = blockIdx.x;
        int t0 = blockIdx.y * 16;
        int k  = tid >> 2, oo = (tid & 3) * 4;
        float4 v0 = make_float4(qts[k][oo], qts[k][oo + 1], qts[k][oo + 2], qts[k][oo + 3]);
        *(float4*)&qT[((size_t)b * DD + k) * SS + t0 + oo] = v0;
    }
}

// ------- K3: Vb[b][bk][:] + cnt; 512 threads, 4-way token split --------------
__global__ __launch_bounds__(512) void k_vb(const float* __restrict__ v,
        const int* __restrict__ bucket, float* __restrict__ Vb,
        int* __restrict__ cnt) {
    int b  = blockIdx.x;                           // 0..7  (XCD = batch)
    int bk = blockIdx.y;                           // 0..31
    int tid = threadIdx.x;
    __shared__ int bkt_sh[512];
    __shared__ float red[3][128];
    bkt_sh[tid] = bucket[b * SS + tid];
    __syncthreads();
    int d = tid & 127, part = tid >> 7;            // 4 parts x 128 tokens
    const float* vbp = v + (size_t)b * SS * DD + d;
    float acc = 0.f;
    #pragma unroll 8
    for (int i = 0; i < 128; ++i) {
        int tok = part * 128 + i;
        float val = vbp[(size_t)tok * DD];
        acc += (bkt_sh[tok] == bk) ? val : 0.f;
    }
    if (part > 0) red[part - 1][d] = acc;
    __syncthreads();
    if (part == 0)
        Vb[(size_t)((b << 5) + bk) * DD + d] = acc + red[0][d] + red[1][d] + red[2][d];
    if (tid < 64) {
        int c = 0;
        #pragma unroll
        for (int i = 0; i < 8; ++i) c += (bkt_sh[tid * 8 + i] == bk) ? 1 : 0;
        #pragma unroll
        for (int o = 1; o < 64; o <<= 1) c += __shfl_xor(c, o, 64);
        if (tid == 0) cnt[(b << 5) + bk] = c;
    }
}

// ------ K5: fused encoder layer; 16-row strips, Z/R folded into consumers ----
__global__ __launch_bounds__(512, 4) void k_enc(const float* __restrict__ qT,
        const float* __restrict__ q, const float* __restrict__ v,
        const int* __restrict__ bucket, const int* __restrict__ cnt,
        const float* __restrict__ Vb,
        const float* __restrict__ g, const float* __restrict__ lb,
        const float* __restrict__ W1, const float* __restrict__ b1,
        const float* __restrict__ W2, const float* __restrict__ b2,
        float* __restrict__ x) {
    int bz = blockIdx.x, s0 = blockIdx.y * 16;     // XCD = batch
    int tid = threadIdx.x;
    __shared__ __align__(16) float qs[16][128];    // q strip -> LN(attn) -> ffn in/residual
    __shared__ __align__(16) float cs[16][512];    // G -> e -> c -> (reuse) h
    __shared__ __align__(16) float osh[4][16][128];// per-kh split-K partials
    __shared__ int   bkt[512];
    __shared__ float Wsh[16][32];
    __shared__ float rsh[16][32];
    __shared__ float Msh[16];
    __shared__ float cntf[32];
    __shared__ int   bssh[16];
    {
        int r = tid >> 5, kq = (tid & 31) * 4;
        *(float4*)&qs[r][kq] = *(const float4*)&q[(size_t)(bz * SS + s0 + r) * DD + kq];
    }
    bkt[tid] = bucket[bz * SS + tid];
    if (tid < 32) cntf[tid] = (float)cnt[(bz << 5) + tid];
    if (tid < 16) bssh[tid] = bucket[bz * SS + s0 + tid];
    Wsh[tid >> 5][tid & 31] = 0.f;
    __syncthreads();
    const float scale = 0.088388347648318447f;
    // ---- Phase G: split-K2 x 2 row-octets x 128 col-quads, 8-row micro ----
    {
        int kh   = tid >> 8;                       // 0..1 : k half (64)
        int rg   = (tid >> 7) & 1;                 // row octet 0..1
        int slot = tid & 127;                      // col quad (512 cols)
        float4 acc[8];
        #pragma unroll
        for (int i = 0; i < 8; ++i) acc[i] = make_float4(0.f, 0.f, 0.f, 0.f);
        const float* qtb = qT + (size_t)bz * DD * SS + (size_t)kh * 64 * SS + slot * 4;
        for (int gg = 0; gg < 16; ++gg) {
            int kb = kh * 64 + gg * 4;
            float4 a[8];
            #pragma unroll
            for (int i = 0; i < 8; ++i) a[i] = *(const float4*)&qs[rg * 8 + i][kb];
            #pragma unroll
            for (int j = 0; j < 4; ++j) {
                float4 b4 = *(const float4*)&qtb[(size_t)(gg * 4 + j) * SS];
                #pragma unroll
                for (int i = 0; i < 8; ++i) {
                    float c = (j == 0) ? a[i].x : (j == 1) ? a[i].y : (j == 2) ? a[i].z : a[i].w;
                    acc[i].x += c * b4.x; acc[i].y += c * b4.y;
                    acc[i].z += c * b4.z; acc[i].w += c * b4.w;
                }
            }
        }
        if (kh == 1) {
            #pragma unroll
            for (int i = 0; i < 8; ++i)
                *(float4*)&cs[rg * 8 + i][slot * 4] = acc[i];
        }
        __syncthreads();
        if (kh == 0) {
            #pragma unroll
            for (int i = 0; i < 8; ++i) {
                float4 p = *(const float4*)&cs[rg * 8 + i][slot * 4];
                p.x = (p.x + acc[i].x) * scale;
                p.y = (p.y + acc[i].y) * scale;
                p.z = (p.z + acc[i].z) * scale;
                p.w = (p.w + acc[i].w) * scale;
                *(float4*)&cs[rg * 8 + i][slot * 4] = p;
            }
        }
        __syncthreads();
    }
    // ---- row max (>=0) : 16 rows x 32 lanes ----
    int row = tid >> 5, l = tid & 31;
    {
        float m = 0.f;
        #pragma unroll
        for (int i = 0; i < 16; ++i) m = fmaxf(m, cs[row][l + 32 * i]);
        #pragma unroll
        for (int o = 1; o < 32; o <<= 1) m = fmaxf(m, __shfl_xor(m, o, 32));
        if (l == 0) Msh[row] = m;
    }
    __syncthreads();
    // ---- exp + per-bucket sums ----
    {
        float Ms = Msh[row];
        #pragma unroll
        for (int i = 0; i < 16; ++i) {
            int c = l + 32 * i;
            float ev = __expf(cs[row][c] - Ms);
            cs[row][c] = ev;
            atomicAdd(&Wsh[row][bkt[c]], ev);
        }
    }
    __syncthreads();
    // ---- rsh with Z folded in (broadcast LDS reads, free) ----
    {
        float z = 0.f;
        #pragma unroll
        for (int i = 0; i < NBK; ++i) z += Wsh[row][i];
        rsh[row][l] = 1.0f / (z - Wsh[row][l] + cntf[l] * __expf(-Msh[row]));
    }
    __syncthreads();
    // ---- transform c = e * (R - r_{b_t}) with R folded in ----
    {
        int bs = bssh[row];
        float R = 0.f;
        #pragma unroll
        for (int i = 0; i < NBK; ++i) R += (i == bs) ? 0.f : rsh[row][i];
        #pragma unroll
        for (int i = 0; i < 16; ++i) {
            int c = l + 32 * i;
            int bc = bkt[c];
            float rsel = (bc == bs) ? 0.f : rsh[row][bc];
            cs[row][c] *= (R - rsel);
        }
    }
    __syncthreads();
    // ---- C@V: split-K4 x 4 row-quads x 32 col-quads; partials -> osh[kh] ----
    {
        int kh = tid >> 7;                         // 0..3 : k chunk of 128
        int rg = (tid >> 5) & 3;                   // row quad
        int cp = tid & 31;                         // col quad over D
        float4 acc[4];
        #pragma unroll
        for (int i = 0; i < 4; ++i) acc[i] = make_float4(0.f, 0.f, 0.f, 0.f);
        const float* vb_base = v + (size_t)bz * SS * DD + cp * 4;
        for (int gg = 0; gg < 32; ++gg) {
            int kb = kh * 128 + gg * 4;
            float4 a[4];
            #pragma unroll
            for (int i = 0; i < 4; ++i) a[i] = *(const float4*)&cs[rg * 4 + i][kb];
            #pragma unroll
            for (int j = 0; j < 4; ++j) {
                float4 vj = *(const float4*)&vb_base[(size_t)(kb + j) * DD];
                #pragma unroll
                for (int i = 0; i < 4; ++i) {
                    float c = (j == 0) ? a[i].x : (j == 1) ? a[i].y : (j == 2) ? a[i].z : a[i].w;
                    acc[i].x += c * vj.x; acc[i].y += c * vj.y;
                    acc[i].z += c * vj.z; acc[i].w += c * vj.w;
                }
            }
        }
        if (kh == 0) {                             // fold uniform term into kh0 partial
            float4 vs = make_float4(0.f, 0.f, 0.f, 0.f);
            #pragma unroll
            for (int i = 0; i < NBK; ++i) {
                float4 t = *(const float4*)&Vb[(size_t)((bz << 5) + i) * DD + cp * 4];
                vs.x += t.x; vs.y += t.y; vs.z += t.z; vs.w += t.w;
            }
            const float inv512 = 1.0f / 512.0f;
            #pragma unroll
            for (int i = 0; i < 4; ++i) {
                int r = rg * 4 + i;
                int bs = bssh[r];
                float4 vb4 = *(const float4*)&Vb[(size_t)((bz << 5) + bs) * DD + cp * 4];
                acc[i].x += (vs.x - vb4.x) * inv512;
                acc[i].y += (vs.y - vb4.y) * inv512;
                acc[i].z += (vs.z - vb4.z) * inv512;
                acc[i].w += (vs.w - vb4.w) * inv512;
            }
        }
        #pragma unroll
        for (int i = 0; i < 4; ++i)
            *(float4*)&osh[kh][rg * 4 + i][cp * 4] = acc[i];
        __syncthreads();
    }
    // ---- LayerNorm(attn), merging 4 partials -> qs (ffn input + residual) ----
    {
        float4 p0 = *(const float4*)&osh[0][row][l * 4];
        float4 p1 = *(const float4*)&osh[1][row][l * 4];
        float4 p2 = *(const float4*)&osh[2][row][l * 4];
        float4 p3 = *(const float4*)&osh[3][row][l * 4];
        float4 val;
        val.x = p0.x + p1.x + p2.x + p3.x;
        val.y = p0.y + p1.y + p2.y + p3.y;
        val.z = p0.z + p1.z + p2.z + p3.z;
        val.w = p0.w + p1.w + p2.w + p3.w;
        float s = val.x + val.y + val.z + val.w;
        float ss = val.x * val.x + val.y * val.y + val.z * val.z + val.w * val.w;
        #pragma unroll
        for (int o = 1; o < 32; o <<= 1) {
            s  += __shfl_xor(s, o, 32);
            ss += __shfl_xor(ss, o, 32);
        }
        float mean = s * (1.f / 128.f);
        float var = ss * (1.f / 128.f) - mean * mean;
        float rstd = rsqrtf(var + 1e-5f);
        float4 gv = *(const float4*)&g[l * 4];
        float4 bv = *(const float4*)&lb[l * 4];
        float4 out;
        out.x = (val.x - mean) * rstd * gv.x + bv.x;
        out.y = (val.y - mean) * rstd * gv.y + bv.y;
        out.z = (val.z - mean) * rstd * gv.z + bv.z;
        out.w = (val.w - mean) * rstd * gv.w + bv.w;
        *(float4*)&qs[row][l * 4] = out;
    }
    __syncthreads();
    // ---- Phase B: h = relu(qs@W1+b1) -> cs (reused as h) ----
    {
        int kh   = tid >> 8;                       // 0..1 : k half (64)
        int rg   = (tid >> 7) & 1;                 // row octet
        int slot = tid & 127;                      // col quad (512 cols)
        float4 acc[8];
        #pragma unroll
        for (int i = 0; i < 8; ++i) acc[i] = make_float4(0.f, 0.f, 0.f, 0.f);
        for (int gg = 0; gg < 16; ++gg) {
            int kb = kh * 64 + gg * 4;
            float4 a[8];
            #pragma unroll
            for (int i = 0; i < 8; ++i) a[i] = *(const float4*)&qs[rg * 8 + i][kb];
            #pragma unroll
            for (int j = 0; j < 4; ++j) {
                float4 w = *(const float4*)&W1[(size_t)(kb + j) * HH + slot * 4];
                #pragma unroll
                for (int i = 0; i < 8; ++i) {
                    float c = (j == 0) ? a[i].x : (j == 1) ? a[i].y : (j == 2) ? a[i].z : a[i].w;
                    acc[i].x += c * w.x; acc[i].y += c * w.y;
                    acc[i].z += c * w.z; acc[i].w += c * w.w;
                }
            }
        }
        if (kh == 1) {
            #pragma unroll
            for (int i = 0; i < 8; ++i)
                *(float4*)&cs[rg * 8 + i][slot * 4] = acc[i];
        }
        __syncthreads();
        if (kh == 0) {
            float4 bi = *(const float4*)&b1[slot * 4];
            #pragma unroll
            for (int i = 0; i < 8; ++i) {
                float4 p = *(const float4*)&cs[rg * 8 + i][slot * 4];
                p.x = fmaxf(p.x + acc[i].x + bi.x, 0.f);
                p.y = fmaxf(p.y + acc[i].y + bi.y, 0.f);
                p.z = fmaxf(p.z + acc[i].z + bi.z, 0.f);
                p.w = fmaxf(p.w + acc[i].w + bi.w, 0.f);
                *(float4*)&cs[rg * 8 + i][slot * 4] = p;
            }
        }
        __syncthreads();
    }
    // ---- Phase C: y = h@W2 (+b2+residual in kh0); partials -> osh[kh] ----
    {
        int kh = tid >> 7;                         // 0..3 : k chunk of 128
        int rg = (tid >> 5) & 3;                   // row quad
        int cp = tid & 31;                         // col quad over D
        float4 acc[4];
        #pragma unroll
        for (int i = 0; i < 4; ++i) acc[i] = make_float4(0.f, 0.f, 0.f, 0.f);
        for (int gg = 0; gg < 32; ++gg) {
            int kb = kh * 128 + gg * 4;
            float4 a[4];
            #pragma unroll
            for (int i = 0; i < 4; ++i) a[i] = *(const float4*)&cs[rg * 4 + i][kb];
            #pragma unroll
            for (int j = 0; j < 4; ++j) {
                float4 w = *(const float4*)&W2[(size_t)(kb + j) * DD + cp * 4];
                #pragma unroll
                for (int i = 0; i < 4; ++i) {
                    float c = (j == 0) ? a[i].x : (j == 1) ? a[i].y : (j == 2) ? a[i].z : a[i].w;
                    acc[i].x += c * w.x; acc[i].y += c * w.y;
                    acc[i].z += c * w.z; acc[i].w += c * w.w;
                }
            }
        }
        if (kh == 0) {
            float4 bi = *(const float4*)&b2[cp * 4];
            #pragma unroll
            for (int i = 0; i < 4; ++i) {
                int r = rg * 4 + i;
                float4 res = *(const float4*)&qs[r][cp * 4];
                acc[i].x += bi.x + res.x;
                acc[i].y += bi.y + res.y;
                acc[i].z += bi.z + res.z;
                acc[i].w += bi.w + res.w;
            }
        }
        #pragma unroll
        for (int i = 0; i < 4; ++i)
            *(float4*)&osh[kh][rg * 4 + i][cp * 4] = acc[i];
        __syncthreads();
    }
    // ---- LayerNorm(ffn), merging 4 partials -> global x ----
    {
        float4 p0 = *(const float4*)&osh[0][row][l * 4];
        float4 p1 = *(const float4*)&osh[1][row][l * 4];
        float4 p2 = *(const float4*)&osh[2][row][l * 4];
        float4 p3 = *(const float4*)&osh[3][row][l * 4];
        float4 val;
        val.x = p0.x + p1.x + p2.x + p3.x;
        val.y = p0.y + p1.y + p2.y + p3.y;
        val.z = p0.z + p1.z + p2.z + p3.z;
        val.w = p0.w + p1.w + p2.w + p3.w;
        float s = val.x + val.y + val.z + val.w;
        float ss = val.x * val.x + val.y * val.y + val.z * val.z + val.w * val.w;
        #pragma unroll
        for (int o = 1; o < 32; o <<= 1) {
            s  += __shfl_xor(s, o, 32);
            ss += __shfl_xor(ss, o, 32);
        }
        float mean = s * (1.f / 128.f);
        float var = ss * (1.f / 128.f) - mean * mean;
        float rstd = rsqrtf(var + 1e-5f);
        float4 gv = *(const float4*)&g[l * 4];
        float4 bv = *(const float4*)&lb[l * 4];
        float4 out;
        out.x = (val.x - mean) * rstd * gv.x + bv.x;
        out.y = (val.y - mean) * rstd * gv.y + bv.y;
        out.z = (val.z - mean) * rstd * gv.z + bv.z;
        out.w = (val.w - mean) * rstd * gv.w + bv.w;
        *(float4*)&x[(size_t)(bz * SS + s0 + row) * DD + l * 4] = out;
    }
}

// ---------------- K9: out = x_flat @ Wm + bm (split-K + atomics) -------------
__global__ __launch_bounds__(256) void k_final(const float* __restrict__ x,
        const float* __restrict__ Wm, const float* __restrict__ bm,
        float* __restrict__ out) {
    int b = blockIdx.x, chunk = blockIdx.y;        // XCD = batch; 2048 elems/chunk
    int tid = threadIdx.x;
    const float* xr = x + (size_t)b * 65536 + chunk * 2048;
    const float* wr = Wm + (size_t)(chunk * 2048) * 6;
    float p[6] = {0.f, 0.f, 0.f, 0.f, 0.f, 0.f};
    #pragma unroll
    for (int it = 0; it < 2; ++it) {
        int j = (tid + 256 * it) * 4;              // float4 over 2048 elems
        float4 xv = *(const float4*)&xr[j];
        const float* w = wr + (size_t)j * 6;
        float4 w0 = *(const float4*)&w[0];
        float4 w1 = *(const float4*)&w[4];
        float4 w2 = *(const float4*)&w[8];
        float4 w3 = *(const float4*)&w[12];
        float4 w4 = *(const float4*)&w[16];
        float4 w5 = *(const float4*)&w[20];
        p[0] += xv.x * w0.x + xv.y * w1.z + xv.z * w3.x + xv.w * w4.z;
        p[1] += xv.x * w0.y + xv.y * w1.w + xv.z * w3.y + xv.w * w4.w;
        p[2] += xv.x * w0.z + xv.y * w2.x + xv.z * w3.z + xv.w * w5.x;
        p[3] += xv.x * w0.w + xv.y * w2.y + xv.z * w3.w + xv.w * w5.y;
        p[4] += xv.x * w1.x + xv.y * w2.z + xv.z * w4.x + xv.w * w5.z;
        p[5] += xv.x * w1.y + xv.y * w2.w + xv.z * w4.y + xv.w * w5.w;
    }
    #pragma unroll
    for (int o = 0; o < 6; ++o)
        #pragma unroll
        for (int off = 1; off < 64; off <<= 1)
            p[o] += __shfl_xor(p[o], off, 64);
    __shared__ float red[4][6];
    int wv = tid >> 6;
    if ((tid & 63) == 0)
        #pragma unroll
        for (int o = 0; o < 6; ++o) red[wv][o] = p[o];
    __syncthreads();
    if (tid < 6) {
        float sv = red[0][tid] + red[1][tid] + red[2][tid] + red[3][tid];
        if (chunk == 0) sv += bm[tid];
        atomicAdd(&out[b * 6 + tid], sv);
    }
}

// ---------------- orchestration ----------------------------------------------
extern "C" void kernel_launch(void* const* d_in, const int* in_sizes, int n_in,
                              void* d_out, int out_size, void* d_ws, size_t ws_size,
                              hipStream_t stream) {
    const int*   inputs = (const int*)  d_in[0];
    const float* emb    = (const float*)d_in[1];
    const float* pe     = (const float*)d_in[2];
    const float* hyp    = (const float*)d_in[3];
    const float* Wq     = (const float*)d_in[4];
    const float* bq     = (const float*)d_in[5];
    const float* Wv     = (const float*)d_in[6];
    const float* bv     = (const float*)d_in[7];
    const float* ln_g   = (const float*)d_in[8];
    const float* ln_b   = (const float*)d_in[9];
    const float* W1     = (const float*)d_in[10];
    const float* b1     = (const float*)d_in[11];
    const float* W2     = (const float*)d_in[12];
    const float* b2     = (const float*)d_in[13];
    const float* Wm     = (const float*)d_in[14];
    const float* bm     = (const float*)d_in[15];

    float* F = (float*)d_ws;
    float* x     = F + 0;          // 524288
    float* q     = F + 524288;     // 524288
    float* v     = F + 1048576;    // 524288
    float* qT    = F + 1572864;    // 524288  [b][k][t]
    float* Vb    = F + 2097152;    // 32768   (plain stores)
    int*   cnt   = (int*)(F + 2129920);  // 256 ints
    int*   bucket= (int*)(F + 2130176);  // 4096 ints

    hipMemsetAsync(d_out, 0, (size_t)out_size * 4, stream);

    for (int enc = 0; enc < 2; ++enc) {
        k_qvb<<<dim3(8, 32), 512, 0, stream>>>(x, inputs, emb, pe, enc == 0 ? 1 : 0,
                                               Wq, bq, Wv, bv, hyp, q, v, qT, bucket);
        k_vb<<<dim3(8, 32), 512, 0, stream>>>(v, bucket, Vb, cnt);
        k_enc<<<dim3(8, 32), 512, 0, stream>>>(qT, q, v, bucket, cnt, Vb,
                                               ln_g, ln_b, W1, b1, W2, b2, x);
    }
    k_final<<<dim3(8, 32), 256, 0, stream>>>(x, Wm, bm, (float*)d_out);
}